// Round 14
// baseline (98.073 us; speedup 1.0000x reference)
//
#include <hip/hip_runtime.h>
#include <float.h>

#define NT 32768
#define DIM 2048
#define NE 64
#define TAU 1e-3f
#define CHUNK 64
#define NCH (DIM / CHUNK)   // 32 chunks

typedef __attribute__((ext_vector_type(8))) short short8;
typedef __attribute__((ext_vector_type(4))) float f32x4;

__device__ __forceinline__ unsigned short f2bf(float f) {
    unsigned u = __float_as_uint(f);
    u += 0x7fffu + ((u >> 16) & 1u);          // RNE
    return (unsigned short)(u >> 16);
}
__device__ __forceinline__ float bf2f(unsigned short h) {
    return __uint_as_float(((unsigned)h) << 16);
}

// Pack gw into MFMA-B fragment order, split hi/lo bf16 (RNE):
// wpk[et][ksg][lane][j] = gw[et*16 + (lane&15)][ksg*32 + (lane>>4)*8 + j]
__global__ __launch_bounds__(256)
void prep_w(const float* __restrict__ gw, unsigned short* __restrict__ wph,
            unsigned short* __restrict__ wpl, int* __restrict__ cnt) {
    const int gid  = blockIdx.x * 256 + threadIdx.x;   // 16384 threads
    const int lane = gid & 63;
    const int ksg  = (gid >> 6) & 63;
    const int et   = gid >> 12;
    const int e    = et * 16 + (lane & 15);
    const int k0   = ksg * 32 + (lane >> 4) * 8;

    float4 v0 = *(const float4*)(gw + (size_t)e * DIM + k0);
    float4 v1 = *(const float4*)(gw + (size_t)e * DIM + k0 + 4);
    float xf[8] = {v0.x, v0.y, v0.z, v0.w, v1.x, v1.y, v1.z, v1.w};
    short8 h, l;
#pragma unroll
    for (int j = 0; j < 8; ++j) {
        unsigned short hh = f2bf(xf[j]);
        h[j] = (short)hh;
        l[j] = (short)f2bf(xf[j] - bf2f(hh));
    }
    *(short8*)(wph + (size_t)gid * 8) = h;
    *(short8*)(wpl + (size_t)gid * 8) = l;
    if (gid == 0) *cnt = 0;
}

// truncation split of 8 fp32 into bf16 hi/lo planes
__device__ __forceinline__ void split8(float4 a0, float4 a1, short8& h, short8& l) {
    float f[8] = {a0.x, a0.y, a0.z, a0.w, a1.x, a1.y, a1.z, a1.w};
#pragma unroll
    for (int j = 0; j < 8; ++j) {
        unsigned u = __float_as_uint(f[j]);
        h[j] = (short)(unsigned short)(u >> 16);
        float lo = f[j] - __uint_as_float(u & 0xffff0000u);
        l[j] = (short)(unsigned short)(__float_as_uint(lo) >> 16);
    }
}

__global__ __launch_bounds__(512, 4)
void router_mfma(const float* __restrict__ x,
                 const unsigned short* __restrict__ wph,
                 const unsigned short* __restrict__ wpl,
                 float* __restrict__ out,
                 int* __restrict__ cnt, int* __restrict__ list) {
    // 32 KB: 2 dbuf x fp32 x-chunk [64 tok][64 k], XOR-swizzled; epilogue aliases lm[64][68]
    __shared__ __align__(16) unsigned char smem[32768];

    const int tid  = threadIdx.x;
    const int lane = tid & 63;
    const int wid  = __builtin_amdgcn_readfirstlane(tid >> 6);
    const int tg   = wid >> 2;                 // token half 0..1
    const int et   = wid & 3;                  // 16-expert tile
    const int t0   = blockIdx.x * 64;

    // staging: thread -> (token = tid>>3, 32-byte group g = tid&7); raw fp32
    const int stok = tid >> 3;
    const int sg   = tid & 7;
    const unsigned st_off = (unsigned)(stok * 256 + ((sg * 32) ^ ((stok & 7) << 5)));
    const float* xrow = x + (size_t)(t0 + stok) * DIM + sg * 8;

    // compute-side read offsets: row = tg*32 + tt*16 + (lane&15); swz = (lane&7)<<5
    const unsigned swz = (unsigned)((lane & 7) << 5);
    unsigned rbase[2], koff[2];
#pragma unroll
    for (int tt = 0; tt < 2; ++tt)
        rbase[tt] = (unsigned)((tg * 32 + tt * 16 + (lane & 15)) * 256);
#pragma unroll
    for (int kg = 0; kg < 2; ++kg)
        koff[kg] = (unsigned)((kg * 128 + (lane >> 4) * 32)) ^ swz;

    f32x4 accP[2], accQ[2];
#pragma unroll
    for (int tt = 0; tt < 2; ++tt)
#pragma unroll
        for (int j = 0; j < 4; ++j) { accP[tt][j] = 0.f; accQ[tt][j] = 0.f; }

    float4 xa, xb;
    short8 Bh0[2], Bl0[2], Bh1[2], Bl1[2];

#define LOADX(c_) { xa = *(const float4*)(xrow + (c_) * CHUNK); \
                    xb = *(const float4*)(xrow + (c_) * CHUNK + 4); }

#define STOREX(buf_) { unsigned char* p_ = smem + (buf_) * 16384 + st_off; \
                       *(float4*)p_ = xa; *(float4*)(p_ + 16) = xb; }

#define BLOAD(bk_, c_) { _Pragma("unroll") for (int kg = 0; kg < 2; ++kg) { \
        size_t o_ = (((size_t)et * 64 + ((c_) * 2 + kg)) * 64 + lane) * 8; \
        Bh##bk_[kg] = *(const short8*)(wph + o_); \
        Bl##bk_[kg] = *(const short8*)(wpl + o_); } }

#define MFMA_PHASE(buf_, bk_) { _Pragma("unroll") for (int tt = 0; tt < 2; ++tt) \
    _Pragma("unroll") for (int kg = 0; kg < 2; ++kg) { \
        const unsigned char* pa_ = smem + (buf_) * 16384 + rbase[tt] + koff[kg]; \
        float4 a0_ = *(const float4*)pa_; \
        float4 a1_ = *(const float4*)(pa_ + 16); \
        short8 Ah_, Al_; \
        split8(a0_, a1_, Ah_, Al_); \
        accP[tt] = __builtin_amdgcn_mfma_f32_16x16x32_bf16(Ah_, Bh##bk_[kg], accP[tt], 0, 0, 0); \
        accQ[tt] = __builtin_amdgcn_mfma_f32_16x16x32_bf16(Ah_, Bl##bk_[kg], accQ[tt], 0, 0, 0); \
        accQ[tt] = __builtin_amdgcn_mfma_f32_16x16x32_bf16(Al_, Bh##bk_[kg], accQ[tt], 0, 0, 0); } }

// counted barrier: drain LDS ops only; global loads stay in flight
#define BARSYNC { asm volatile("s_waitcnt lgkmcnt(0)" ::: "memory"); \
                  __builtin_amdgcn_sched_barrier(0); \
                  __builtin_amdgcn_s_barrier(); }

    // prologue: chunk 0 -> regs -> buf0; B(0) -> bank0
    LOADX(0)
    BLOAD(0, 0)
    STOREX(0)
    BARSYNC

    // steady state: c = 0..29 in even/odd pairs (branch-free bodies)
#pragma unroll 1
    for (int cc = 0; cc < 15; ++cc) {
        const int c0 = 2 * cc;                 // <= 28
        LOADX(c0 + 1)
        BLOAD(1, c0 + 1)
        MFMA_PHASE(0, 0)
        STOREX(1)
        BARSYNC
        const int c1 = c0 + 1;                 // <= 29
        LOADX(c1 + 1)
        BLOAD(0, c1 + 1)
        MFMA_PHASE(1, 1)
        STOREX(0)
        BARSYNC
    }
    // tail c = 30: stage chunk 31, no further x load
    LOADX(31)
    BLOAD(1, 31)
    MFMA_PHASE(0, 0)
    STOREX(1)
    BARSYNC
    // tail c = 31
    MFMA_PHASE(1, 1)
    __syncthreads();                           // full drain before aliasing lm

#undef LOADX
#undef STOREX
#undef BLOAD
#undef MFMA_PHASE
#undef BARSYNC

    // merge logits into aliased LDS
    float* lmf = (float*)smem;                 // [64][68]
#pragma unroll
    for (int tt = 0; tt < 2; ++tt)
#pragma unroll
        for (int jr = 0; jr < 4; ++jr)
            lmf[(tg * 32 + tt * 16 + (lane >> 4) * 4 + jr) * 68 + et * 16 + (lane & 15)] =
                accP[tt][jr] + accQ[tt][jr];
    __syncthreads();

    // ---- epilogue: 8 threads per token, 8 experts each ----
    float* mout = out;
    float* wout = out + (size_t)NT * NE;
    float* iout = wout + (size_t)NT * 2;

    const int t   = tid >> 3;                  // local token 0..63
    const int s   = tid & 7;                   // 8-expert segment
    const int tok = t0 + t;

    float vv[8];
    {
        float4 p0 = *(const float4*)&lmf[t * 68 + s * 8];
        float4 p1 = *(const float4*)&lmf[t * 68 + s * 8 + 4];
        vv[0] = p0.x; vv[1] = p0.y; vv[2] = p0.z; vv[3] = p0.w;
        vv[4] = p1.x; vv[5] = p1.y; vv[6] = p1.z; vv[7] = p1.w;
    }

    float m1 = -FLT_MAX, m2 = -FLT_MAX, m3 = -FLT_MAX;
    int   i1 = NE, i2 = NE, i3 = NE;
    auto ins = [&](float v, int e) {
        bool b1 = (v > m1) || (v == m1 && e < i1);
        bool b2 = (v > m2) || (v == m2 && e < i2);
        bool b3 = (v > m3) || (v == m3 && e < i3);
        if (b1)      { m3 = m2; i3 = i2; m2 = m1; i2 = i1; m1 = v; i1 = e; }
        else if (b2) { m3 = m2; i3 = i2; m2 = v; i2 = e; }
        else if (b3) { m3 = v; i3 = e; }
    };
#pragma unroll
    for (int j = 0; j < 8; ++j) ins(vv[j], s * 8 + j);
#pragma unroll
    for (int off = 1; off <= 4; off <<= 1) {   // merge across the 8-lane group
        float om1 = __shfl_xor(m1, off, 64); int oi1 = __shfl_xor(i1, off, 64);
        float om2 = __shfl_xor(m2, off, 64); int oi2 = __shfl_xor(i2, off, 64);
        float om3 = __shfl_xor(m3, off, 64); int oi3 = __shfl_xor(i3, off, 64);
        ins(om1, oi1); ins(om2, oi2); ins(om3, oi3);
    }

    float ed  = expf(m2 - m1);
    float inv = 1.f / (1.f + ed);

    {
        float4 mv0, mv1;
        int e0 = s * 8;
        mv0.x = (e0     == i1 || e0     == i2) ? 1.f : 0.f;
        mv0.y = (e0 + 1 == i1 || e0 + 1 == i2) ? 1.f : 0.f;
        mv0.z = (e0 + 2 == i1 || e0 + 2 == i2) ? 1.f : 0.f;
        mv0.w = (e0 + 3 == i1 || e0 + 3 == i2) ? 1.f : 0.f;
        mv1.x = (e0 + 4 == i1 || e0 + 4 == i2) ? 1.f : 0.f;
        mv1.y = (e0 + 5 == i1 || e0 + 5 == i2) ? 1.f : 0.f;
        mv1.z = (e0 + 6 == i1 || e0 + 6 == i2) ? 1.f : 0.f;
        mv1.w = (e0 + 7 == i1 || e0 + 7 == i2) ? 1.f : 0.f;
        *(float4*)(mout + (size_t)tok * NE + e0)     = mv0;
        *(float4*)(mout + (size_t)tok * NE + e0 + 4) = mv1;
    }

    if (s == 0) {
        *(float2*)(wout + 2 * tok) = make_float2(inv, ed * inv);
        *(float2*)(iout + 2 * tok) = make_float2((float)i1, (float)i2);
        if ((m1 - m2 < TAU) || (m2 - m3 < TAU)) {
            int slot = atomicAdd(cnt, 1);
            list[slot] = tok;
        }
    }
}

// Exact fp32 recompute of flagged (near-tie) tokens; overwrites their outputs.
__global__ __launch_bounds__(256)
void repair(const float* __restrict__ x, const float* __restrict__ gw,
            float* __restrict__ out, const int* __restrict__ cnt,
            const int* __restrict__ list) {
    __shared__ float red[64][5];
    const int n   = *cnt;
    const int tid = threadIdx.x;
    const int e   = tid & 63, qq = tid >> 6;     // expert, k-quarter

    float* mout = out;
    float* wout = out + (size_t)NT * NE;
    float* iout = wout + (size_t)NT * 2;

    for (int i = blockIdx.x; i < n; i += gridDim.x) {
        const int tok = list[i];
        const float* xr = x + (size_t)tok * DIM + qq * 512;
        const float* wr = gw + (size_t)e * DIM + qq * 512;
        float a = 0.f;
        for (int j = 0; j < 512; j += 4) {
            float4 xv = *(const float4*)(xr + j);
            float4 wv = *(const float4*)(wr + j);
            a = fmaf(xv.x, wv.x, a); a = fmaf(xv.y, wv.y, a);
            a = fmaf(xv.z, wv.z, a); a = fmaf(xv.w, wv.w, a);
        }
        red[e][qq] = a;
        __syncthreads();
        if (tid < 64) {
            float v = ((red[e][0] + red[e][1]) + red[e][2]) + red[e][3];
            float m1 = v, m2 = -FLT_MAX; int i1 = e, i2 = NE;
#pragma unroll
            for (int off = 1; off <= 32; off <<= 1) {
                float om1 = __shfl_xor(m1, off, 64); int oi1 = __shfl_xor(i1, off, 64);
                float om2 = __shfl_xor(m2, off, 64); int oi2 = __shfl_xor(i2, off, 64);
                bool selfFirst = (m1 > om1) || (m1 == om1 && i1 < oi1);
                if (selfFirst) {
                    if (!((m2 > om1) || (m2 == om1 && i2 < oi1))) { m2 = om1; i2 = oi1; }
                } else {
                    bool c = (m1 > om2) || (m1 == om2 && i1 < oi2);
                    if (c) { m2 = m1; i2 = i1; } else { m2 = om2; i2 = oi2; }
                    m1 = om1; i1 = oi1;
                }
            }
            float ed  = expf(m2 - m1);
            float inv = 1.f / (1.f + ed);
            mout[(size_t)tok * NE + e] = (e == i1 || e == i2) ? 1.f : 0.f;
            if (e == 0) {
                *(float2*)(wout + 2 * tok) = make_float2(inv, ed * inv);
                *(float2*)(iout + 2 * tok) = make_float2((float)i1, (float)i2);
            }
        }
        __syncthreads();
    }
}

extern "C" void kernel_launch(void* const* d_in, const int* in_sizes, int n_in,
                              void* d_out, int out_size, void* d_ws, size_t ws_size,
                              hipStream_t stream) {
    const float* x  = (const float*)d_in[0];
    const float* gw = (const float*)d_in[1];
    float* out = (float*)d_out;

    unsigned short* wph = (unsigned short*)d_ws;         // 256 KB (packed hi)
    unsigned short* wpl = wph + (size_t)NE * DIM;        // 256 KB (packed lo)
    int* cnt  = (int*)(wpl + (size_t)NE * DIM);          // 4 B
    int* list = cnt + 1;                                 // 128 KB

    prep_w<<<dim3(64), dim3(256), 0, stream>>>(gw, wph, wpl, cnt);
    router_mfma<<<dim3(NT / 64), dim3(512), 0, stream>>>(x, wph, wpl, out, cnt, list);
    repair<<<dim3(256), dim3(256), 0, stream>>>(x, gw, out, cnt, list);
}